// Round 1
// baseline (138.065 us; speedup 1.0000x reference)
//
#include <hip/hip_runtime.h>
#include <math.h>

// Problem constants (from reference: B=1024, N=4096, fp32).
#define BATCH    1024
#define NPTS     4096
#define SPLIT    4                 // partial blocks per batch
#define CHUNK    (NPTS / SPLIT)    // 1024 points per partial block
#define THREADS  256
#define WAVES    4
#define NACC     23
#define WSSTR    24                // padded partial stride (floats)
#define RPAD     264               // reduction row stride (256+8): conflict-free

typedef float fx4 __attribute__((ext_vector_type(4)));

// Accumulator layout (23 floats):
//  0      : sw        = sum w
//  1..3   : mw[i]     = sum m_i w
//  4..6   : yw[i]     = sum y_i w
//  7..12  : Mw sym    = (00,01,02,11,12,22)
// 13..21  : MY[i][j]  row-major
// 22     : yy        = sum (y.y) w

// R6 theory: previous async-LDS kernel ran at 856 GB/s (13% of HBM) because
// 56 KB LDS capped occupancy at 2 blocks/CU and the stage->vmcnt(0)->compute
// phase structure idled the vmem pipe. New shape: canonical streaming
// reduction — 4096 small blocks, ONE round of 7 fx4 loads per thread (no
// loop for the compiler to sink), 16-24 waves/CU of TLP hides HBM latency.
// Partials go to workspace; a tiny second kernel does the 13x13 epilogue.

__global__ __launch_bounds__(THREADS) void partial_sums(
    const float* __restrict__ m,   // (B,3,N)
    const float* __restrict__ y,   // (B,3,N)
    const float* __restrict__ w,   // (B,1,N)
    float* __restrict__ ws)        // (B*SPLIT, WSSTR) partials
{
    const int blk  = blockIdx.x;
    const int b    = blk >> 2;          // batch       (SPLIT == 4)
    const int s    = blk & 3;           // split index
    const int tid  = threadIdx.x;
    const int lane = tid & 63;
    const int wave = tid >> 6;

    const size_t mb  = (size_t)b * 3 * NPTS;
    const int    off = s * CHUNK + tid * 4;   // 16B-aligned, coalesced

    // One round of loads per thread: 7 independent global_load_dwordx4.
    // All issue up front; TLP across ~16-24 waves/CU hides HBM latency.
    const fx4 vm0 = *(const fx4*)(m + mb + 0 * NPTS + off);
    const fx4 vm1 = *(const fx4*)(m + mb + 1 * NPTS + off);
    const fx4 vm2 = *(const fx4*)(m + mb + 2 * NPTS + off);
    const fx4 vy0 = *(const fx4*)(y + mb + 0 * NPTS + off);
    const fx4 vy1 = *(const fx4*)(y + mb + 1 * NPTS + off);
    const fx4 vy2 = *(const fx4*)(y + mb + 2 * NPTS + off);
    const fx4 vw  = *(const fx4*)(w + (size_t)b * NPTS + off);

    float acc[NACC];
#pragma unroll
    for (int i = 0; i < NACC; ++i) acc[i] = 0.f;

#pragma unroll
    for (int e = 0; e < 4; ++e) {
        const float wv  = vw[e];
        const float m0v = vm0[e], m1v = vm1[e], m2v = vm2[e];
        const float y0v = vy0[e], y1v = vy1[e], y2v = vy2[e];
        const float wm0 = wv * m0v, wm1 = wv * m1v, wm2 = wv * m2v;
        acc[0]  += wv;
        acc[1]  += wm0;        acc[2]  += wm1;        acc[3]  += wm2;
        acc[4]  += wv * y0v;   acc[5]  += wv * y1v;   acc[6]  += wv * y2v;
        acc[7]  += wm0 * m0v;  acc[8]  += wm0 * m1v;  acc[9]  += wm0 * m2v;
        acc[10] += wm1 * m1v;  acc[11] += wm1 * m2v;  acc[12] += wm2 * m2v;
        acc[13] += wm0 * y0v;  acc[14] += wm0 * y1v;  acc[15] += wm0 * y2v;
        acc[16] += wm1 * y0v;  acc[17] += wm1 * y1v;  acc[18] += wm1 * y2v;
        acc[19] += wm2 * y0v;  acc[20] += wm2 * y1v;  acc[21] += wm2 * y2v;
        acc[22] += wv * (y0v * y0v + y1v * y1v + y2v * y2v);
    }

    // ---- Block reduction: LDS fold (256 -> 64 lanes) + wave-0 butterfly ----
    // acc-major, row stride 264 (264 % 32 == 8): conflict-free writes/reads.
    __shared__ float red[NACC * RPAD];      // 24.3 KB
#pragma unroll
    for (int i = 0; i < NACC; ++i) red[i * RPAD + tid] = acc[i];
    __syncthreads();

    if (wave == 0) {
        float part[NACC];
#pragma unroll
        for (int i = 0; i < NACC; ++i) {
            const float* row = &red[i * RPAD + lane];
            part[i] = row[0] + row[64] + row[128] + row[192];
        }
#pragma unroll
        for (int i = 0; i < NACC; ++i) {
            float v = part[i];
            v += __shfl_xor(v, 32, 64);
            v += __shfl_xor(v, 16, 64);
            v += __shfl_xor(v, 8, 64);
            v += __shfl_xor(v, 4, 64);
            v += __shfl_xor(v, 2, 64);
            v += __shfl_xor(v, 1, 64);
            part[i] = v;
        }
        if (lane == 0) {
            float* o = ws + (size_t)blk * WSSTR;
#pragma unroll
            for (int i = 0; i < NACC; ++i) o[i] = part[i];  // contiguous
        }
    }
}

// ---- Kernel 2: sum SPLIT partials, assemble Q, normalize, store ----
__global__ __launch_bounds__(THREADS) void epilogue_kernel(
    const float* __restrict__ ws,  // (B*SPLIT, WSSTR)
    float* __restrict__ out)       // Qn (B*169) | scales (B) | offsets (B)
{
    const int b    = blockIdx.x;
    const int tid  = threadIdx.x;
    const int lane = tid & 63;
    const int wave = tid >> 6;

    __shared__ float sums[NACC];
    __shared__ float sqred[WAVES];
    __shared__ float scale_s;

    if (tid < NACC) {
        const float* p = ws + (size_t)b * SPLIT * WSSTR + tid;
        sums[tid] = p[0 * WSSTR] + p[1 * WSSTR] + p[2 * WSSTR] + p[3 * WSSTR];
    }
    __syncthreads();

    // ---- Epilogue: assemble Q (one entry per thread), normalize, store ----
    float qv = 0.f;
    if (tid < 169) {
        const int r = tid / 13, c = tid % 13;
        const float* mwv = &sums[1];
        const float* ywv = &sums[4];
        auto Mwf = [&](int i, int j) -> float {
            if (i > j) { int t = i; i = j; j = t; }
            int idx = (i == 0) ? j : ((i == 1) ? (j + 2) : 5);
            return sums[7 + idx];
        };
        auto MYf = [&](int i, int j) -> float { return sums[13 + i * 3 + j]; };

        if (r == 0) {
            if (c == 0)            qv = 0.f;
            else if (c <= 9)       qv = -MYf((c - 1) / 3, (c - 1) % 3);   // Qch
            else                   qv = ywv[c - 10];
        } else if (c == 0) {
            if (r <= 9)            qv = -MYf((r - 1) / 3, (r - 1) % 3);   // Qch
            else                   qv = ywv[r - 10];
        } else if (r <= 9 && c <= 9) {                                    // Qcc
            int a = r - 1, d = c - 1;
            int i = a / 3, k = a % 3, j = d / 3, l = d % 3;
            qv = (k == l) ? Mwf(i, j) : 0.f;
        } else if (r <= 9) {                                              // Qct
            int a = r - 1, i = a / 3, k = a % 3, l = c - 10;
            qv = (k == l) ? -mwv[i] : 0.f;
        } else if (c <= 9) {                                              // Qct^T
            int a = c - 1, i = a / 3, k = a % 3, l = r - 10;
            qv = (k == l) ? -mwv[i] : 0.f;
        } else {                                                          // Qtt
            qv = (r == c) ? sums[0] : 0.f;
        }
    }

    // Block-wide sum of squares -> scale.
    float sq = (tid < 169) ? qv * qv : 0.f;
    sq += __shfl_xor(sq, 32, 64);
    sq += __shfl_xor(sq, 16, 64);
    sq += __shfl_xor(sq, 8, 64);
    sq += __shfl_xor(sq, 4, 64);
    sq += __shfl_xor(sq, 2, 64);
    sq += __shfl_xor(sq, 1, 64);
    if (lane == 0) sqred[wave] = sq;
    __syncthreads();
    if (tid == 0) {
        scale_s = sqrtf(sqred[0] + sqred[1] + sqred[2] + sqred[3]);
    }
    __syncthreads();

    const float inv_scale = 1.0f / scale_s;
    if (tid < 169) {
        out[(size_t)b * 169 + tid] = qv * inv_scale;
    }
    if (tid == 0) {
        out[(size_t)BATCH * 169 + b]         = scale_s;   // scales
        out[(size_t)BATCH * 169 + BATCH + b] = sums[22];  // offsets (yy)
    }
}

extern "C" void kernel_launch(void* const* d_in, const int* in_sizes, int n_in,
                              void* d_out, int out_size, void* d_ws, size_t ws_size,
                              hipStream_t stream) {
    const float* m = (const float*)d_in[0];  // keypoints_3D_src (B,3,N)
    const float* y = (const float*)d_in[1];  // keypoints_3D_trg (B,3,N)
    const float* w = (const float*)d_in[2];  // weights (B,1,N)
    float* out = (float*)d_out;
    float* ws  = (float*)d_ws;               // needs 1024*4*24*4 B = 393 KB

    partial_sums<<<BATCH * SPLIT, THREADS, 0, stream>>>(m, y, w, ws);
    epilogue_kernel<<<BATCH, THREADS, 0, stream>>>(ws, out);
}

// Round 3
// 137.908 us; speedup vs baseline: 1.0011x; 1.0011x over previous
//
#include <hip/hip_runtime.h>
#include <math.h>

// Problem constants (from reference: B=1024, N=4096, fp32).
#define BATCH    1024
#define NPTS     4096
#define SPLIT    4                 // partial blocks per batch
#define CHUNK    (NPTS / SPLIT)    // 1024 points per partial block
#define THREADS  256
#define WAVES    4
#define NACC     23
#define RPAD     264               // reduction row stride (256+8): conflict-free

typedef float fx4 __attribute__((ext_vector_type(4)));

// Accumulator layout (23 floats):
//  0      : sw        = sum w
//  1..3   : mw[i]     = sum m_i w
//  4..6   : yw[i]     = sum y_i w
//  7..12  : Mw sym    = (00,01,02,11,12,22)
// 13..21  : MY[i][j]  row-major
// 22     : yy        = sum (y.y) w

// R8 = R7 resubmitted (R7 never ran: GPU acquisition timeout).
// R7 theory: R6's rocprof showed the timed path dominated by 256 MiB
// __amd_rocclr_fillBufferAligned dispatches (~40 us each) — the WORKSPACE
// being re-poisoned per iteration (rigor.md "re-poison semantics"). Our
// kernels were already <40 us. Fix: drop d_ws entirely; stash the 92
// partial floats per batch inside that batch's own 169-float Qn slot of
// `out` (kernel1 block (b,s) writes out[b*169+s*23..+23); kernel2 block b
// reads its own partials, __syncthreads, then overwrites all 169).
// No cross-block overlap; same-stream dispatch ordering gives visibility.

__global__ __launch_bounds__(THREADS) void partial_sums(
    const float* __restrict__ m,   // (B,3,N)
    const float* __restrict__ y,   // (B,3,N)
    const float* __restrict__ w,   // (B,1,N)
    float* __restrict__ out)       // partials -> out[b*169 + s*23 .. +23)
{
    const int blk  = blockIdx.x;
    const int b    = blk >> 2;          // batch       (SPLIT == 4)
    const int s    = blk & 3;           // split index
    const int tid  = threadIdx.x;
    const int lane = tid & 63;
    const int wave = tid >> 6;

    const size_t mb  = (size_t)b * 3 * NPTS;
    const int    off = s * CHUNK + tid * 4;   // 16B-aligned, coalesced

    // One round of loads per thread: 7 independent global_load_dwordx4.
    // All issue up front; TLP across ~16-24 waves/CU hides HBM latency.
    const fx4 vm0 = *(const fx4*)(m + mb + 0 * NPTS + off);
    const fx4 vm1 = *(const fx4*)(m + mb + 1 * NPTS + off);
    const fx4 vm2 = *(const fx4*)(m + mb + 2 * NPTS + off);
    const fx4 vy0 = *(const fx4*)(y + mb + 0 * NPTS + off);
    const fx4 vy1 = *(const fx4*)(y + mb + 1 * NPTS + off);
    const fx4 vy2 = *(const fx4*)(y + mb + 2 * NPTS + off);
    const fx4 vw  = *(const fx4*)(w + (size_t)b * NPTS + off);

    float acc[NACC];
#pragma unroll
    for (int i = 0; i < NACC; ++i) acc[i] = 0.f;

#pragma unroll
    for (int e = 0; e < 4; ++e) {
        const float wv  = vw[e];
        const float m0v = vm0[e], m1v = vm1[e], m2v = vm2[e];
        const float y0v = vy0[e], y1v = vy1[e], y2v = vy2[e];
        const float wm0 = wv * m0v, wm1 = wv * m1v, wm2 = wv * m2v;
        acc[0]  += wv;
        acc[1]  += wm0;        acc[2]  += wm1;        acc[3]  += wm2;
        acc[4]  += wv * y0v;   acc[5]  += wv * y1v;   acc[6]  += wv * y2v;
        acc[7]  += wm0 * m0v;  acc[8]  += wm0 * m1v;  acc[9]  += wm0 * m2v;
        acc[10] += wm1 * m1v;  acc[11] += wm1 * m2v;  acc[12] += wm2 * m2v;
        acc[13] += wm0 * y0v;  acc[14] += wm0 * y1v;  acc[15] += wm0 * y2v;
        acc[16] += wm1 * y0v;  acc[17] += wm1 * y1v;  acc[18] += wm1 * y2v;
        acc[19] += wm2 * y0v;  acc[20] += wm2 * y1v;  acc[21] += wm2 * y2v;
        acc[22] += wv * (y0v * y0v + y1v * y1v + y2v * y2v);
    }

    // ---- Block reduction: LDS fold (256 -> 64 lanes) + wave-0 butterfly ----
    // acc-major, row stride 264 (264 % 32 == 8): conflict-free writes/reads.
    __shared__ float red[NACC * RPAD];      // 24.3 KB
#pragma unroll
    for (int i = 0; i < NACC; ++i) red[i * RPAD + tid] = acc[i];
    __syncthreads();

    if (wave == 0) {
        float part[NACC];
#pragma unroll
        for (int i = 0; i < NACC; ++i) {
            const float* row = &red[i * RPAD + lane];
            part[i] = row[0] + row[64] + row[128] + row[192];
        }
#pragma unroll
        for (int i = 0; i < NACC; ++i) {
            float v = part[i];
            v += __shfl_xor(v, 32, 64);
            v += __shfl_xor(v, 16, 64);
            v += __shfl_xor(v, 8, 64);
            v += __shfl_xor(v, 4, 64);
            v += __shfl_xor(v, 2, 64);
            v += __shfl_xor(v, 1, 64);
            part[i] = v;
        }
        if (lane == 0) {
            // Partials live inside this batch's own Qn slot (overwritten
            // by the epilogue kernel after it reads them).
            float* o = out + (size_t)b * 169 + s * NACC;
#pragma unroll
            for (int i = 0; i < NACC; ++i) o[i] = part[i];  // contiguous
        }
    }
}

// ---- Kernel 2: sum SPLIT partials, assemble Q, normalize, store ----
__global__ __launch_bounds__(THREADS) void epilogue_kernel(
    float* __restrict__ out)       // Qn (B*169) | scales (B) | offsets (B)
{
    const int b    = blockIdx.x;
    const int tid  = threadIdx.x;
    const int lane = tid & 63;
    const int wave = tid >> 6;

    __shared__ float sums[NACC];
    __shared__ float sqred[WAVES];
    __shared__ float scale_s;

    if (tid < NACC) {
        const float* p = out + (size_t)b * 169 + tid;
        sums[tid] = p[0 * NACC] + p[1 * NACC] + p[2 * NACC] + p[3 * NACC];
    }
    __syncthreads();

    // ---- Epilogue: assemble Q (one entry per thread), normalize, store ----
    float qv = 0.f;
    if (tid < 169) {
        const int r = tid / 13, c = tid % 13;
        const float* mwv = &sums[1];
        const float* ywv = &sums[4];
        auto Mwf = [&](int i, int j) -> float {
            if (i > j) { int t = i; i = j; j = t; }
            int idx = (i == 0) ? j : ((i == 1) ? (j + 2) : 5);
            return sums[7 + idx];
        };
        auto MYf = [&](int i, int j) -> float { return sums[13 + i * 3 + j]; };

        if (r == 0) {
            if (c == 0)            qv = 0.f;
            else if (c <= 9)       qv = -MYf((c - 1) / 3, (c - 1) % 3);   // Qch
            else                   qv = ywv[c - 10];
        } else if (c == 0) {
            if (r <= 9)            qv = -MYf((r - 1) / 3, (r - 1) % 3);   // Qch
            else                   qv = ywv[r - 10];
        } else if (r <= 9 && c <= 9) {                                    // Qcc
            int a = r - 1, d = c - 1;
            int i = a / 3, k = a % 3, j = d / 3, l = d % 3;
            qv = (k == l) ? Mwf(i, j) : 0.f;
        } else if (r <= 9) {                                              // Qct
            int a = r - 1, i = a / 3, k = a % 3, l = c - 10;
            qv = (k == l) ? -mwv[i] : 0.f;
        } else if (c <= 9) {                                              // Qct^T
            int a = c - 1, i = a / 3, k = a % 3, l = r - 10;
            qv = (k == l) ? -mwv[i] : 0.f;
        } else {                                                          // Qtt
            qv = (r == c) ? sums[0] : 0.f;
        }
    }

    // Block-wide sum of squares -> scale.
    float sq = (tid < 169) ? qv * qv : 0.f;
    sq += __shfl_xor(sq, 32, 64);
    sq += __shfl_xor(sq, 16, 64);
    sq += __shfl_xor(sq, 8, 64);
    sq += __shfl_xor(sq, 4, 64);
    sq += __shfl_xor(sq, 2, 64);
    sq += __shfl_xor(sq, 1, 64);
    if (lane == 0) sqred[wave] = sq;
    __syncthreads();
    if (tid == 0) {
        scale_s = sqrtf(sqred[0] + sqred[1] + sqred[2] + sqred[3]);
    }
    __syncthreads();

    const float inv_scale = 1.0f / scale_s;
    if (tid < 169) {
        out[(size_t)b * 169 + tid] = qv * inv_scale;   // overwrites partials
    }
    if (tid == 0) {
        out[(size_t)BATCH * 169 + b]         = scale_s;   // scales
        out[(size_t)BATCH * 169 + BATCH + b] = sums[22];  // offsets (yy)
    }
}

extern "C" void kernel_launch(void* const* d_in, const int* in_sizes, int n_in,
                              void* d_out, int out_size, void* d_ws, size_t ws_size,
                              hipStream_t stream) {
    const float* m = (const float*)d_in[0];  // keypoints_3D_src (B,3,N)
    const float* y = (const float*)d_in[1];  // keypoints_3D_trg (B,3,N)
    const float* w = (const float*)d_in[2];  // weights (B,1,N)
    float* out = (float*)d_out;

    partial_sums<<<BATCH * SPLIT, THREADS, 0, stream>>>(m, y, w, out);
    epilogue_kernel<<<BATCH, THREADS, 0, stream>>>(out);
}